// Round 1
// baseline (659.277 us; speedup 1.0000x reference)
//
#include <hip/hip_runtime.h>

#define NB 64
#define NPRED 25200
#define NCAND 2048
#define NSEL 1024
#define NDET 300
#define NBINS 8192
#define CONF_T 0.25f
#define IOU_T 0.45f
#define BASE_BITS 0x3E800000u   // bits of 0.25f

__device__ __forceinline__ float sigmoidf_(float x) {
    return 1.0f / (1.0f + expf(-x));
}

// ---------------------------------------------------------------- scores
// score = valid ? obj*sigmoid(max raw_cls) : 0   (monotonicity of sigmoid)
__global__ void k_score(const float* __restrict__ r0,
                        const float* __restrict__ r1,
                        const float* __restrict__ r2,
                        float* __restrict__ scores) {
    int tid = blockIdx.x * blockDim.x + threadIdx.x;
    if (tid >= NB * NPRED) return;
    int img = tid / NPRED;
    int n = tid - img * NPRED;
    const float* src;
    int local, cells;
    if (n < 19200)      { src = r0; local = n;         cells = 6400; }
    else if (n < 24000) { src = r1; local = n - 19200; cells = 1600; }
    else                { src = r2; local = n - 24000; cells = 400;  }
    long base = ((long)img * 3 * cells + local) * 20;
    const float4* p = (const float4*)(src + base + 4);   // raw[4..19], 16B aligned
    float4 v0 = p[0], v1 = p[1], v2 = p[2], v3 = p[3];
    float obj = sigmoidf_(v0.x);
    float m = v0.y;
    m = fmaxf(m, v0.z); m = fmaxf(m, v0.w);
    m = fmaxf(m, v1.x); m = fmaxf(m, v1.y); m = fmaxf(m, v1.z); m = fmaxf(m, v1.w);
    m = fmaxf(m, v2.x); m = fmaxf(m, v2.y); m = fmaxf(m, v2.z); m = fmaxf(m, v2.w);
    m = fmaxf(m, v3.x); m = fmaxf(m, v3.y); m = fmaxf(m, v3.z); m = fmaxf(m, v3.w);
    float best = obj * sigmoidf_(m);
    float sc = (obj > CONF_T && best > CONF_T) ? best : 0.0f;
    scores[tid] = sc;
}

// ---------------------------------------------------------------- select
// Per-image histogram over float bits of (0.25,1.0), find threshold bin such
// that count(bins>T) < 1024 <= count(bins>=T), compact all >= T into cand[]
// as packed keys (scoreBits<<32)|(0xFFFFFFFF-idx). Pad remainder with 0.
__global__ __launch_bounds__(1024) void k_select(const float* __restrict__ scores,
                                                 unsigned long long* __restrict__ cand) {
    __shared__ unsigned int hist[NBINS];
    __shared__ unsigned int bufA[1024];
    __shared__ unsigned int bufB[1024];
    __shared__ unsigned int s_thr;
    __shared__ unsigned int s_cnt;
    int img = blockIdx.x;
    int t = threadIdx.x;
    for (int b = t; b < NBINS; b += 1024) hist[b] = 0;
    if (t == 0) { s_thr = 0; s_cnt = 0; }
    __syncthreads();
    const float* sc = scores + (long)img * NPRED;
    for (int n = t; n < NPRED; n += 1024) {
        float s = sc[n];
        if (s > CONF_T) {
            unsigned bin = (__float_as_uint(s) - BASE_BITS) >> 11;
            if (bin > NBINS - 1u) bin = NBINS - 1u;
            atomicAdd(&hist[bin], 1u);
        }
    }
    __syncthreads();
    // per-thread chunk of 8 bins
    unsigned h[8];
    unsigned cs = 0;
    for (int b = 0; b < 8; ++b) { h[b] = hist[t * 8 + b]; cs += h[b]; }
    bufA[t] = cs;
    __syncthreads();
    // inclusive Hillis-Steele scan over 1024 chunk sums
    unsigned int* srcp = bufA;
    unsigned int* dstp = bufB;
    for (int ofs = 1; ofs < 1024; ofs <<= 1) {
        unsigned v = srcp[t];
        if (t >= ofs) v += srcp[t - ofs];
        dstp[t] = v;
        __syncthreads();
        unsigned int* tmp = srcp; srcp = dstp; dstp = tmp;
    }
    unsigned total = srcp[1023];
    unsigned above = total - srcp[t];   // count in bins with chunk index > t
    if (total >= NSEL) {
        unsigned c = above;
        for (int b = 7; b >= 0; --b) {
            unsigned ci = c + h[b];
            if (c < NSEL && ci >= NSEL) {
                s_thr = BASE_BITS + ((unsigned)(t * 8 + b) << 11);
            }
            c = ci;
        }
    }
    __syncthreads();
    unsigned thr = s_thr;
    unsigned long long* cd = cand + (long)img * NCAND;
    for (int n = t; n < NPRED; n += 1024) {
        float s = sc[n];
        if (s > CONF_T) {
            unsigned bits = __float_as_uint(s);
            if (bits >= thr) {
                unsigned pos = atomicAdd(&s_cnt, 1u);
                if (pos < NCAND)
                    cd[pos] = ((unsigned long long)bits << 32) |
                              (unsigned long long)(0xFFFFFFFFu - (unsigned)n);
            }
        }
    }
    __syncthreads();
    for (unsigned pos = s_cnt + (unsigned)t; pos < NCAND; pos += 1024) cd[pos] = 0ull;
}

// ---------------------------------------------------------------- sort
// In-LDS bitonic sort of 2048 keys, descending => exact lax.top_k order
// (score desc, idx asc on ties via the ~idx low word).
__global__ __launch_bounds__(1024) void k_sort(const unsigned long long* __restrict__ cand,
                                               float* __restrict__ sel_score,
                                               int* __restrict__ sel_idx) {
    __shared__ unsigned long long s[NCAND];
    int img = blockIdx.x, t = threadIdx.x;
    s[t]        = cand[(long)img * NCAND + t];
    s[t + 1024] = cand[(long)img * NCAND + t + 1024];
    __syncthreads();
    for (int k = 2; k <= NCAND; k <<= 1) {
        for (int j = k >> 1; j > 0; j >>= 1) {
            for (int e = t; e < NCAND; e += 1024) {
                int p = e ^ j;
                if (p > e) {
                    unsigned long long a = s[e], b = s[p];
                    bool up = ((e & k) == 0);
                    if ((a < b) == up) { s[e] = b; s[p] = a; }
                }
            }
            __syncthreads();
        }
    }
    unsigned long long key = s[t];
    float scv = __uint_as_float((unsigned)(key >> 32));
    int idx = (int)(0xFFFFFFFFu - (unsigned)(key & 0xFFFFFFFFull));
    sel_score[img * NSEL + t] = scv;
    sel_idx[img * NSEL + t] = idx;
}

// ---------------------------------------------------------------- decode selected
__global__ void k_decode(const float* __restrict__ r0, const float* __restrict__ r1,
                         const float* __restrict__ r2, const float* __restrict__ strd,
                         const float* __restrict__ ag,
                         const float* __restrict__ sel_score,
                         const int* __restrict__ sel_idx,
                         float* __restrict__ sel_box, float* __restrict__ sel_cls) {
    int t = blockIdx.x * blockDim.x + threadIdx.x;
    if (t >= NB * NSEL) return;
    int img = t >> 10;
    float scv = sel_score[t];
    float4 bb = make_float4(0.f, 0.f, 0.f, 0.f);
    float cls = 0.0f;
    if (scv > CONF_T) {
        int n = sel_idx[t];
        const float* src;
        int a, y, x, nx, cells, sidx;
        if (n < 19200) {
            sidx = 0; src = r0; nx = 80; cells = 6400;
            int l = n;            a = l / 6400; int r = l - a * 6400; y = r / 80; x = r - y * 80;
        } else if (n < 24000) {
            sidx = 1; src = r1; nx = 40; cells = 1600;
            int l = n - 19200;    a = l / 1600; int r = l - a * 1600; y = r / 40; x = r - y * 40;
        } else {
            sidx = 2; src = r2; nx = 20; cells = 400;
            int l = n - 24000;    a = l / 400;  int r = l - a * 400;  y = r / 20; x = r - y * 20;
        }
        (void)nx;
        long base = ((long)img * 3 * cells + (long)a * cells + (long)(n - ((sidx == 0) ? 0 : (sidx == 1 ? 19200 : 24000)) - a * cells)) * 20;
        // simpler: base from (img,a,y,x)
        base = (((long)img * 3 + a) * cells + (long)y * ((sidx==0)?80:(sidx==1?40:20)) + x) * 20;
        const float4* p = (const float4*)(src + base);
        float4 v0 = p[0];               // raw[0..3]
        float st = strd[sidx];
        float aw = ag[(sidx * 3 + a) * 2 + 0];
        float ah = ag[(sidx * 3 + a) * 2 + 1];
        float cx = (sigmoidf_(v0.x) * 2.0f - 0.5f + (float)x) * st;
        float cy = (sigmoidf_(v0.y) * 2.0f - 0.5f + (float)y) * st;
        float tw = sigmoidf_(v0.z) * 2.0f;
        float th = sigmoidf_(v0.w) * 2.0f;
        float w = tw * tw * aw;
        float h = th * th * ah;
        bb.x = cx - w * 0.5f;
        bb.y = cy - h * 0.5f;
        bb.z = cx + w * 0.5f;
        bb.w = cy + h * 0.5f;
        float4 c0 = p[1], c1 = p[2], c2 = p[3], c3 = p[4];   // raw[4..19]
        float vals[15] = { c0.y, c0.z, c0.w,
                           c1.x, c1.y, c1.z, c1.w,
                           c2.x, c2.y, c2.z, c2.w,
                           c3.x, c3.y, c3.z, c3.w };
        float bv = vals[0]; int bi = 0;
        for (int k = 1; k < 15; ++k) if (vals[k] > bv) { bv = vals[k]; bi = k; }
        cls = (float)bi;
    }
    ((float4*)sel_box)[t] = bb;
    sel_cls[t] = cls;
}

// ---------------------------------------------------------------- IoU mask
// mask[img][i][w] bit b set <=> j=w*64+b > i and IoU(box_i,box_j) > 0.45
__global__ __launch_bounds__(256) void k_mask(const float* __restrict__ sel_box,
                                              unsigned long long* __restrict__ mask) {
    __shared__ float4 box[NSEL];
    __shared__ float area[NSEL];
    int img  = blockIdx.x >> 6;
    int iblk = blockIdx.x & 63;
    int t = threadIdx.x;
    const float4* bsrc = (const float4*)sel_box + (long)img * NSEL;
    for (int e = t; e < NSEL; e += 256) {
        float4 b = bsrc[e];
        box[e] = b;
        area[e] = (b.z - b.x) * (b.w - b.y);
    }
    __syncthreads();
    int li = t >> 4;            // 0..15
    int w  = t & 15;            // word 0..15
    int i = iblk * 16 + li;
    float4 bi = box[i];
    float ai = area[i];
    unsigned long long m = 0;
    for (int b = 0; b < 64; ++b) {
        int j = w * 64 + b;
        if (j > i) {
            float4 bj = box[j];
            float iw = fminf(bi.z, bj.z) - fmaxf(bi.x, bj.x);
            float ih = fminf(bi.w, bj.w) - fmaxf(bi.y, bj.y);
            iw = fmaxf(iw, 0.0f);
            ih = fmaxf(ih, 0.0f);
            float inter = iw * ih;
            float iou = inter / (ai + area[j] - inter + 1e-7f);
            if (iou > IOU_T) m |= (1ull << b);
        }
    }
    mask[((long)img * NSEL + i) * 16 + w] = m;
}

// ---------------------------------------------------------------- greedy sweep
// Single wave per image; lanes 0..15 hold the 16 keep words.
__global__ __launch_bounds__(64) void k_sweep(const float* __restrict__ sel_score,
                                              const unsigned long long* __restrict__ mask,
                                              unsigned long long* __restrict__ keep) {
    int img = blockIdx.x;
    int lane = threadIdx.x;
    unsigned long long kw = 0;
    if (lane < 16) {
        const float* sc = sel_score + img * NSEL + lane * 64;
        for (int b = 0; b < 64; ++b)
            if (sc[b] > CONF_T) kw |= (1ull << b);
    }
    const unsigned long long* mrow = mask + (long)img * NSEL * 16;
    for (int i = 0; i < NSEL; ++i) {
        unsigned long long cur = __shfl(kw, i >> 6);
        if ((cur >> (i & 63)) & 1ull) {
            if (lane < 16) kw &= ~mrow[(long)i * 16 + lane];
        }
    }
    if (lane < 16) keep[img * 16 + lane] = kw;
}

// ---------------------------------------------------------------- output
__global__ __launch_bounds__(1024) void k_out(const float* __restrict__ sel_score,
                                              const float* __restrict__ sel_box,
                                              const float* __restrict__ sel_cls,
                                              const unsigned long long* __restrict__ keep,
                                              float* __restrict__ out) {
    __shared__ unsigned int wsum[16];
    int img = blockIdx.x, t = threadIdx.x;
    float* o = out + (long)img * NDET * 6;
    for (int e = t; e < NDET * 6; e += 1024) o[e] = 0.0f;
    bool kept = (keep[img * 16 + (t >> 6)] >> (t & 63)) & 1ull;
    unsigned long long bal = __ballot(kept);
    int lane = t & 63, wid = t >> 6;
    int lrank = __popcll(bal & ((1ull << lane) - 1ull));
    if (lane == 0) wsum[wid] = (unsigned)__popcll(bal);
    __syncthreads();
    int off = 0;
    for (int ww = 0; ww < wid; ++ww) off += (int)wsum[ww];
    int rank = off + lrank;
    if (kept && rank < NDET) {
        float4 b = ((const float4*)sel_box)[img * NSEL + t];
        float s = sel_score[img * NSEL + t];
        float c = sel_cls[img * NSEL + t];
        float* row = o + rank * 6;
        row[0] = b.x; row[1] = b.y; row[2] = b.z; row[3] = b.w;
        row[4] = s;   row[5] = c;
    }
}

// ---------------------------------------------------------------- launch
extern "C" void kernel_launch(void* const* d_in, const int* in_sizes, int n_in,
                              void* d_out, int out_size, void* d_ws, size_t ws_size,
                              hipStream_t stream) {
    const float* r0   = (const float*)d_in[0];
    const float* r1   = (const float*)d_in[1];
    const float* r2   = (const float*)d_in[2];
    const float* strd = (const float*)d_in[3];
    const float* ag   = (const float*)d_in[4];

    char* ws = (char*)d_ws;
    size_t off = 0;
    auto alloc = [&](size_t bytes) -> void* {
        void* p = ws + off;
        off += (bytes + 255) & ~(size_t)255;
        return p;
    };
    float* scores              = (float*)alloc((size_t)NB * NPRED * 4);
    unsigned long long* cand   = (unsigned long long*)alloc((size_t)NB * NCAND * 8);
    float* sel_score           = (float*)alloc((size_t)NB * NSEL * 4);
    int* sel_idx               = (int*)alloc((size_t)NB * NSEL * 4);
    float* sel_box             = (float*)alloc((size_t)NB * NSEL * 16);
    float* sel_cls             = (float*)alloc((size_t)NB * NSEL * 4);
    unsigned long long* mask   = (unsigned long long*)alloc((size_t)NB * NSEL * 16 * 8);
    unsigned long long* keep   = (unsigned long long*)alloc((size_t)NB * 16 * 8);
    float* out = (float*)d_out;

    k_score<<<(NB * NPRED + 255) / 256, 256, 0, stream>>>(r0, r1, r2, scores);
    k_select<<<NB, 1024, 0, stream>>>(scores, cand);
    k_sort<<<NB, 1024, 0, stream>>>(cand, sel_score, sel_idx);
    k_decode<<<(NB * NSEL + 255) / 256, 256, 0, stream>>>(r0, r1, r2, strd, ag,
                                                          sel_score, sel_idx, sel_box, sel_cls);
    k_mask<<<NB * 64, 256, 0, stream>>>(sel_box, mask);
    k_sweep<<<NB, 64, 0, stream>>>(sel_score, mask, keep);
    k_out<<<NB, 1024, 0, stream>>>(sel_score, sel_box, sel_cls, keep, out);
}

// Round 2
// 412.889 us; speedup vs baseline: 1.5967x; 1.5967x over previous
//
#include <hip/hip_runtime.h>

#define NB 64
#define NPRED 25200
#define NCAND 2048
#define NSEL 1024
#define NDET 300
#define NBINS 8192
#define CONF_T 0.25f
#define IOU_T 0.45f
#define BASE_BITS 0x3E800000u   // bits of 0.25f

__device__ __forceinline__ float sigmoidf_(float x) {
    return 1.0f / (1.0f + expf(-x));
}

// ---------------------------------------------------------------- scores
// score = valid ? obj*sigmoid(max raw_cls) : 0   (monotonicity of sigmoid)
__global__ void k_score(const float* __restrict__ r0,
                        const float* __restrict__ r1,
                        const float* __restrict__ r2,
                        float* __restrict__ scores) {
    int tid = blockIdx.x * blockDim.x + threadIdx.x;
    if (tid >= NB * NPRED) return;
    int img = tid / NPRED;
    int n = tid - img * NPRED;
    const float* src;
    int local, cells;
    if (n < 19200)      { src = r0; local = n;         cells = 6400; }
    else if (n < 24000) { src = r1; local = n - 19200; cells = 1600; }
    else                { src = r2; local = n - 24000; cells = 400;  }
    long base = ((long)img * 3 * cells + local) * 20;
    const float4* p = (const float4*)(src + base + 4);   // raw[4..19], 16B aligned
    float4 v0 = p[0], v1 = p[1], v2 = p[2], v3 = p[3];
    float obj = sigmoidf_(v0.x);
    float m = v0.y;
    m = fmaxf(m, v0.z); m = fmaxf(m, v0.w);
    m = fmaxf(m, v1.x); m = fmaxf(m, v1.y); m = fmaxf(m, v1.z); m = fmaxf(m, v1.w);
    m = fmaxf(m, v2.x); m = fmaxf(m, v2.y); m = fmaxf(m, v2.z); m = fmaxf(m, v2.w);
    m = fmaxf(m, v3.x); m = fmaxf(m, v3.y); m = fmaxf(m, v3.z); m = fmaxf(m, v3.w);
    float best = obj * sigmoidf_(m);
    float sc = (obj > CONF_T && best > CONF_T) ? best : 0.0f;
    scores[tid] = sc;
}

// ---------------------------------------------------------------- select
__global__ __launch_bounds__(1024) void k_select(const float* __restrict__ scores,
                                                 unsigned long long* __restrict__ cand) {
    __shared__ unsigned int hist[NBINS];
    __shared__ unsigned int bufA[1024];
    __shared__ unsigned int bufB[1024];
    __shared__ unsigned int s_thr;
    __shared__ unsigned int s_cnt;
    int img = blockIdx.x;
    int t = threadIdx.x;
    for (int b = t; b < NBINS; b += 1024) hist[b] = 0;
    if (t == 0) { s_thr = 0; s_cnt = 0; }
    __syncthreads();
    const float* sc = scores + (long)img * NPRED;
    for (int n = t; n < NPRED; n += 1024) {
        float s = sc[n];
        if (s > CONF_T) {
            unsigned bin = (__float_as_uint(s) - BASE_BITS) >> 11;
            if (bin > NBINS - 1u) bin = NBINS - 1u;
            atomicAdd(&hist[bin], 1u);
        }
    }
    __syncthreads();
    unsigned h[8];
    unsigned cs = 0;
    for (int b = 0; b < 8; ++b) { h[b] = hist[t * 8 + b]; cs += h[b]; }
    bufA[t] = cs;
    __syncthreads();
    unsigned int* srcp = bufA;
    unsigned int* dstp = bufB;
    for (int ofs = 1; ofs < 1024; ofs <<= 1) {
        unsigned v = srcp[t];
        if (t >= ofs) v += srcp[t - ofs];
        dstp[t] = v;
        __syncthreads();
        unsigned int* tmp = srcp; srcp = dstp; dstp = tmp;
    }
    unsigned total = srcp[1023];
    unsigned above = total - srcp[t];
    if (total >= NSEL) {
        unsigned c = above;
        for (int b = 7; b >= 0; --b) {
            unsigned ci = c + h[b];
            if (c < NSEL && ci >= NSEL) {
                s_thr = BASE_BITS + ((unsigned)(t * 8 + b) << 11);
            }
            c = ci;
        }
    }
    __syncthreads();
    unsigned thr = s_thr;
    unsigned long long* cd = cand + (long)img * NCAND;
    for (int n = t; n < NPRED; n += 1024) {
        float s = sc[n];
        if (s > CONF_T) {
            unsigned bits = __float_as_uint(s);
            if (bits >= thr) {
                unsigned pos = atomicAdd(&s_cnt, 1u);
                if (pos < NCAND)
                    cd[pos] = ((unsigned long long)bits << 32) |
                              (unsigned long long)(0xFFFFFFFFu - (unsigned)n);
            }
        }
    }
    __syncthreads();
    for (unsigned pos = s_cnt + (unsigned)t; pos < NCAND; pos += 1024) cd[pos] = 0ull;
}

// ---------------------------------------------------------------- sort
__global__ __launch_bounds__(1024) void k_sort(const unsigned long long* __restrict__ cand,
                                               float* __restrict__ sel_score,
                                               int* __restrict__ sel_idx) {
    __shared__ unsigned long long s[NCAND];
    int img = blockIdx.x, t = threadIdx.x;
    s[t]        = cand[(long)img * NCAND + t];
    s[t + 1024] = cand[(long)img * NCAND + t + 1024];
    __syncthreads();
    for (int k = 2; k <= NCAND; k <<= 1) {
        for (int j = k >> 1; j > 0; j >>= 1) {
            for (int e = t; e < NCAND; e += 1024) {
                int p = e ^ j;
                if (p > e) {
                    unsigned long long a = s[e], b = s[p];
                    bool up = ((e & k) == 0);
                    if ((a < b) == up) { s[e] = b; s[p] = a; }
                }
            }
            __syncthreads();
        }
    }
    unsigned long long key = s[t];
    float scv = __uint_as_float((unsigned)(key >> 32));
    int idx = (int)(0xFFFFFFFFu - (unsigned)(key & 0xFFFFFFFFull));
    sel_score[img * NSEL + t] = scv;
    sel_idx[img * NSEL + t] = idx;
}

// ---------------------------------------------------------------- decode selected
__global__ void k_decode(const float* __restrict__ r0, const float* __restrict__ r1,
                         const float* __restrict__ r2, const float* __restrict__ strd,
                         const float* __restrict__ ag,
                         const float* __restrict__ sel_score,
                         const int* __restrict__ sel_idx,
                         float* __restrict__ sel_box, float* __restrict__ sel_cls) {
    int t = blockIdx.x * blockDim.x + threadIdx.x;
    if (t >= NB * NSEL) return;
    int img = t >> 10;
    float scv = sel_score[t];
    float4 bb = make_float4(0.f, 0.f, 0.f, 0.f);
    float cls = 0.0f;
    if (scv > CONF_T) {
        int n = sel_idx[t];
        const float* src;
        int a, y, x, cells, sidx, nxl;
        if (n < 19200) {
            sidx = 0; src = r0; cells = 6400; nxl = 80;
            int l = n;            a = l / 6400; int r = l - a * 6400; y = r / 80; x = r - y * 80;
        } else if (n < 24000) {
            sidx = 1; src = r1; cells = 1600; nxl = 40;
            int l = n - 19200;    a = l / 1600; int r = l - a * 1600; y = r / 40; x = r - y * 40;
        } else {
            sidx = 2; src = r2; cells = 400; nxl = 20;
            int l = n - 24000;    a = l / 400;  int r = l - a * 400;  y = r / 20; x = r - y * 20;
        }
        long base = (((long)img * 3 + a) * cells + (long)y * nxl + x) * 20;
        const float4* p = (const float4*)(src + base);
        float4 v0 = p[0];
        float st = strd[sidx];
        float aw = ag[(sidx * 3 + a) * 2 + 0];
        float ah = ag[(sidx * 3 + a) * 2 + 1];
        float cx = (sigmoidf_(v0.x) * 2.0f - 0.5f + (float)x) * st;
        float cy = (sigmoidf_(v0.y) * 2.0f - 0.5f + (float)y) * st;
        float tw = sigmoidf_(v0.z) * 2.0f;
        float th = sigmoidf_(v0.w) * 2.0f;
        float w = tw * tw * aw;
        float h = th * th * ah;
        bb.x = cx - w * 0.5f;
        bb.y = cy - h * 0.5f;
        bb.z = cx + w * 0.5f;
        bb.w = cy + h * 0.5f;
        float4 c0 = p[1], c1 = p[2], c2 = p[3], c3 = p[4];
        float vals[15] = { c0.y, c0.z, c0.w,
                           c1.x, c1.y, c1.z, c1.w,
                           c2.x, c2.y, c2.z, c2.w,
                           c3.x, c3.y, c3.z, c3.w };
        float bv = vals[0]; int bi = 0;
        for (int k = 1; k < 15; ++k) if (vals[k] > bv) { bv = vals[k]; bi = k; }
        cls = (float)bi;
    }
    ((float4*)sel_box)[t] = bb;
    sel_cls[t] = cls;
}

// ---------------------------------------------------------------- IoU mask
__global__ __launch_bounds__(256) void k_mask(const float* __restrict__ sel_box,
                                              unsigned long long* __restrict__ mask) {
    __shared__ float4 box[NSEL];
    __shared__ float area[NSEL];
    int img  = blockIdx.x >> 6;
    int iblk = blockIdx.x & 63;
    int t = threadIdx.x;
    const float4* bsrc = (const float4*)sel_box + (long)img * NSEL;
    for (int e = t; e < NSEL; e += 256) {
        float4 b = bsrc[e];
        box[e] = b;
        area[e] = (b.z - b.x) * (b.w - b.y);
    }
    __syncthreads();
    int li = t >> 4;            // 0..15
    int w  = t & 15;            // word 0..15
    int i = iblk * 16 + li;
    float4 bi = box[i];
    float ai = area[i];
    unsigned long long m = 0;
    for (int b = 0; b < 64; ++b) {
        int j = w * 64 + b;
        if (j > i) {
            float4 bj = box[j];
            float iw = fminf(bi.z, bj.z) - fmaxf(bi.x, bj.x);
            float ih = fminf(bi.w, bj.w) - fmaxf(bi.y, bj.y);
            iw = fmaxf(iw, 0.0f);
            ih = fmaxf(ih, 0.0f);
            float inter = iw * ih;
            float iou = inter / (ai + area[j] - inter + 1e-7f);
            if (iou > IOU_T) m |= (1ull << b);
        }
    }
    mask[((long)img * NSEL + i) * 16 + w] = m;
}

// ---------------------------------------------------------------- greedy sweep
// One wave per image. Lanes 0..15 hold the 16 keep words (split lo/hi 32-bit).
// Mask rows are register-prefetched (double-buffered, 32 rows/chunk) so the
// only serialized chain is: predicated v_and -> v_readlane -> s_and -> select.
#define SWEEP_CHUNK(kc, CUR, NXT, HALF)                                   \
    {                                                                     \
        if ((kc) + 1 < 32) {                                              \
            _Pragma("unroll")                                             \
            for (int d = 0; d < 32; ++d)                                  \
                NXT[d] = ldv ? lp[((kc) + 1) * 32 * 16 + d * 16] : 0ull;  \
        }                                                                 \
        int widx = (kc) >> 1;                                             \
        _Pragma("unroll")                                                 \
        for (int d = 0; d < 32; ++d) {                                    \
            unsigned cur = (unsigned)__builtin_amdgcn_readlane(           \
                (int)(HALF), widx);                                       \
            unsigned long long mm =                                       \
                (cur & (1u << d)) ? CUR[d] : 0ull;                        \
            kwlo &= ~(unsigned)mm;                                        \
            kwhi &= ~(unsigned)(mm >> 32);                                \
        }                                                                 \
    }

__global__ __launch_bounds__(64) void k_sweep(const float* __restrict__ sel_score,
                                              const unsigned long long* __restrict__ mask,
                                              unsigned long long* __restrict__ keep) {
    int img = blockIdx.x;
    int lane = threadIdx.x;
    const float* sc = sel_score + img * NSEL;
    unsigned long long kw = 0;
    for (int g = 0; g < 16; ++g) {
        unsigned long long bal = __ballot(sc[g * 64 + lane] > CONF_T);
        if (lane == g) kw = bal;
    }
    unsigned kwlo = (unsigned)kw;
    unsigned kwhi = (unsigned)(kw >> 32);
    const unsigned long long* lp = mask + (long)img * NSEL * 16 + lane;
    bool ldv = lane < 16;
    unsigned long long bufA[32], bufB[32];
#pragma unroll
    for (int d = 0; d < 32; ++d) bufA[d] = ldv ? lp[d * 16] : 0ull;
    for (int kc = 0; kc < 32; kc += 2) {
        SWEEP_CHUNK(kc,     bufA, bufB, kwlo);
        SWEEP_CHUNK(kc + 1, bufB, bufA, kwhi);
    }
    if (lane < 16)
        keep[img * 16 + lane] =
            ((unsigned long long)kwhi << 32) | (unsigned long long)kwlo;
}

// ---------------------------------------------------------------- output
__global__ __launch_bounds__(1024) void k_out(const float* __restrict__ sel_score,
                                              const float* __restrict__ sel_box,
                                              const float* __restrict__ sel_cls,
                                              const unsigned long long* __restrict__ keep,
                                              float* __restrict__ out) {
    __shared__ unsigned int wsum[16];
    int img = blockIdx.x, t = threadIdx.x;
    float* o = out + (long)img * NDET * 6;
    for (int e = t; e < NDET * 6; e += 1024) o[e] = 0.0f;
    bool kept = (keep[img * 16 + (t >> 6)] >> (t & 63)) & 1ull;
    unsigned long long bal = __ballot(kept);
    int lane = t & 63, wid = t >> 6;
    int lrank = __popcll(bal & ((1ull << lane) - 1ull));
    if (lane == 0) wsum[wid] = (unsigned)__popcll(bal);
    __syncthreads();
    int off = 0;
    for (int ww = 0; ww < wid; ++ww) off += (int)wsum[ww];
    int rank = off + lrank;
    if (kept && rank < NDET) {
        float4 b = ((const float4*)sel_box)[img * NSEL + t];
        float s = sel_score[img * NSEL + t];
        float c = sel_cls[img * NSEL + t];
        float* row = o + rank * 6;
        row[0] = b.x; row[1] = b.y; row[2] = b.z; row[3] = b.w;
        row[4] = s;   row[5] = c;
    }
}

// ---------------------------------------------------------------- launch
extern "C" void kernel_launch(void* const* d_in, const int* in_sizes, int n_in,
                              void* d_out, int out_size, void* d_ws, size_t ws_size,
                              hipStream_t stream) {
    const float* r0   = (const float*)d_in[0];
    const float* r1   = (const float*)d_in[1];
    const float* r2   = (const float*)d_in[2];
    const float* strd = (const float*)d_in[3];
    const float* ag   = (const float*)d_in[4];

    char* ws = (char*)d_ws;
    size_t off = 0;
    auto alloc = [&](size_t bytes) -> void* {
        void* p = ws + off;
        off += (bytes + 255) & ~(size_t)255;
        return p;
    };
    float* scores              = (float*)alloc((size_t)NB * NPRED * 4);
    unsigned long long* cand   = (unsigned long long*)alloc((size_t)NB * NCAND * 8);
    float* sel_score           = (float*)alloc((size_t)NB * NSEL * 4);
    int* sel_idx               = (int*)alloc((size_t)NB * NSEL * 4);
    float* sel_box             = (float*)alloc((size_t)NB * NSEL * 16);
    float* sel_cls             = (float*)alloc((size_t)NB * NSEL * 4);
    unsigned long long* mask   = (unsigned long long*)alloc((size_t)NB * NSEL * 16 * 8);
    unsigned long long* keep   = (unsigned long long*)alloc((size_t)NB * 16 * 8);
    float* out = (float*)d_out;

    k_score<<<(NB * NPRED + 255) / 256, 256, 0, stream>>>(r0, r1, r2, scores);
    k_select<<<NB, 1024, 0, stream>>>(scores, cand);
    k_sort<<<NB, 1024, 0, stream>>>(cand, sel_score, sel_idx);
    k_decode<<<(NB * NSEL + 255) / 256, 256, 0, stream>>>(r0, r1, r2, strd, ag,
                                                          sel_score, sel_idx, sel_box, sel_cls);
    k_mask<<<NB * 64, 256, 0, stream>>>(sel_box, mask);
    k_sweep<<<NB, 64, 0, stream>>>(sel_score, mask, keep);
    k_out<<<NB, 1024, 0, stream>>>(sel_score, sel_box, sel_cls, keep, out);
}

// Round 3
// 317.609 us; speedup vs baseline: 2.0758x; 1.3000x over previous
//
#include <hip/hip_runtime.h>

#define NB 64
#define NPRED 25200
#define NCAND 2048
#define NSEL 1024
#define NDET 300
#define NBINS 8192
#define CONF_T 0.25f
#define IOU_T 0.45f
#define BASE_BITS 0x3E800000u   // bits of 0.25f

__device__ __forceinline__ float sigmoidf_(float x) {
    return 1.0f / (1.0f + expf(-x));
}

// ---------------------------------------------------------------- scores
// score = valid ? obj*sigmoid(max raw_cls) : 0   (monotonicity of sigmoid)
__global__ void k_score(const float* __restrict__ r0,
                        const float* __restrict__ r1,
                        const float* __restrict__ r2,
                        float* __restrict__ scores) {
    int tid = blockIdx.x * blockDim.x + threadIdx.x;
    if (tid >= NB * NPRED) return;
    int img = tid / NPRED;
    int n = tid - img * NPRED;
    const float* src;
    int local, cells;
    if (n < 19200)      { src = r0; local = n;         cells = 6400; }
    else if (n < 24000) { src = r1; local = n - 19200; cells = 1600; }
    else                { src = r2; local = n - 24000; cells = 400;  }
    long base = ((long)img * 3 * cells + local) * 20;
    const float4* p = (const float4*)(src + base + 4);   // raw[4..19], 16B aligned
    float4 v0 = p[0], v1 = p[1], v2 = p[2], v3 = p[3];
    float obj = sigmoidf_(v0.x);
    float m = v0.y;
    m = fmaxf(m, v0.z); m = fmaxf(m, v0.w);
    m = fmaxf(m, v1.x); m = fmaxf(m, v1.y); m = fmaxf(m, v1.z); m = fmaxf(m, v1.w);
    m = fmaxf(m, v2.x); m = fmaxf(m, v2.y); m = fmaxf(m, v2.z); m = fmaxf(m, v2.w);
    m = fmaxf(m, v3.x); m = fmaxf(m, v3.y); m = fmaxf(m, v3.z); m = fmaxf(m, v3.w);
    float best = obj * sigmoidf_(m);
    float sc = (obj > CONF_T && best > CONF_T) ? best : 0.0f;
    scores[tid] = sc;
}

// ---------------------------------------------------------------- select
__global__ __launch_bounds__(1024) void k_select(const float* __restrict__ scores,
                                                 unsigned long long* __restrict__ cand) {
    __shared__ unsigned int hist[NBINS];
    __shared__ unsigned int bufA[1024];
    __shared__ unsigned int bufB[1024];
    __shared__ unsigned int s_thr;
    __shared__ unsigned int s_cnt;
    int img = blockIdx.x;
    int t = threadIdx.x;
    for (int b = t; b < NBINS; b += 1024) hist[b] = 0;
    if (t == 0) { s_thr = 0; s_cnt = 0; }
    __syncthreads();
    const float* sc = scores + (long)img * NPRED;
    for (int n = t; n < NPRED; n += 1024) {
        float s = sc[n];
        if (s > CONF_T) {
            unsigned bin = (__float_as_uint(s) - BASE_BITS) >> 11;
            if (bin > NBINS - 1u) bin = NBINS - 1u;
            atomicAdd(&hist[bin], 1u);
        }
    }
    __syncthreads();
    unsigned h[8];
    unsigned cs = 0;
    for (int b = 0; b < 8; ++b) { h[b] = hist[t * 8 + b]; cs += h[b]; }
    bufA[t] = cs;
    __syncthreads();
    unsigned int* srcp = bufA;
    unsigned int* dstp = bufB;
    for (int ofs = 1; ofs < 1024; ofs <<= 1) {
        unsigned v = srcp[t];
        if (t >= ofs) v += srcp[t - ofs];
        dstp[t] = v;
        __syncthreads();
        unsigned int* tmp = srcp; srcp = dstp; dstp = tmp;
    }
    unsigned total = srcp[1023];
    unsigned above = total - srcp[t];
    if (total >= NSEL) {
        unsigned c = above;
        for (int b = 7; b >= 0; --b) {
            unsigned ci = c + h[b];
            if (c < NSEL && ci >= NSEL) {
                s_thr = BASE_BITS + ((unsigned)(t * 8 + b) << 11);
            }
            c = ci;
        }
    }
    __syncthreads();
    unsigned thr = s_thr;
    unsigned long long* cd = cand + (long)img * NCAND;
    for (int n = t; n < NPRED; n += 1024) {
        float s = sc[n];
        if (s > CONF_T) {
            unsigned bits = __float_as_uint(s);
            if (bits >= thr) {
                unsigned pos = atomicAdd(&s_cnt, 1u);
                if (pos < NCAND)
                    cd[pos] = ((unsigned long long)bits << 32) |
                              (unsigned long long)(0xFFFFFFFFu - (unsigned)n);
            }
        }
    }
    __syncthreads();
    for (unsigned pos = s_cnt + (unsigned)t; pos < NCAND; pos += 1024) cd[pos] = 0ull;
}

// ---------------------------------------------------------------- sort
__global__ __launch_bounds__(1024) void k_sort(const unsigned long long* __restrict__ cand,
                                               float* __restrict__ sel_score,
                                               int* __restrict__ sel_idx) {
    __shared__ unsigned long long s[NCAND];
    int img = blockIdx.x, t = threadIdx.x;
    s[t]        = cand[(long)img * NCAND + t];
    s[t + 1024] = cand[(long)img * NCAND + t + 1024];
    __syncthreads();
    for (int k = 2; k <= NCAND; k <<= 1) {
        for (int j = k >> 1; j > 0; j >>= 1) {
            for (int e = t; e < NCAND; e += 1024) {
                int p = e ^ j;
                if (p > e) {
                    unsigned long long a = s[e], b = s[p];
                    bool up = ((e & k) == 0);
                    if ((a < b) == up) { s[e] = b; s[p] = a; }
                }
            }
            __syncthreads();
        }
    }
    unsigned long long key = s[t];
    float scv = __uint_as_float((unsigned)(key >> 32));
    int idx = (int)(0xFFFFFFFFu - (unsigned)(key & 0xFFFFFFFFull));
    sel_score[img * NSEL + t] = scv;
    sel_idx[img * NSEL + t] = idx;
}

// ---------------------------------------------------------------- decode selected
__global__ void k_decode(const float* __restrict__ r0, const float* __restrict__ r1,
                         const float* __restrict__ r2, const float* __restrict__ strd,
                         const float* __restrict__ ag,
                         const float* __restrict__ sel_score,
                         const int* __restrict__ sel_idx,
                         float* __restrict__ sel_box, float* __restrict__ sel_cls) {
    int t = blockIdx.x * blockDim.x + threadIdx.x;
    if (t >= NB * NSEL) return;
    int img = t >> 10;
    float scv = sel_score[t];
    float4 bb = make_float4(0.f, 0.f, 0.f, 0.f);
    float cls = 0.0f;
    if (scv > CONF_T) {
        int n = sel_idx[t];
        const float* src;
        int a, y, x, cells, sidx, nxl;
        if (n < 19200) {
            sidx = 0; src = r0; cells = 6400; nxl = 80;
            int l = n;            a = l / 6400; int r = l - a * 6400; y = r / 80; x = r - y * 80;
        } else if (n < 24000) {
            sidx = 1; src = r1; cells = 1600; nxl = 40;
            int l = n - 19200;    a = l / 1600; int r = l - a * 1600; y = r / 40; x = r - y * 40;
        } else {
            sidx = 2; src = r2; cells = 400; nxl = 20;
            int l = n - 24000;    a = l / 400;  int r = l - a * 400;  y = r / 20; x = r - y * 20;
        }
        long base = (((long)img * 3 + a) * cells + (long)y * nxl + x) * 20;
        const float4* p = (const float4*)(src + base);
        float4 v0 = p[0];
        float st = strd[sidx];
        float aw = ag[(sidx * 3 + a) * 2 + 0];
        float ah = ag[(sidx * 3 + a) * 2 + 1];
        float cx = (sigmoidf_(v0.x) * 2.0f - 0.5f + (float)x) * st;
        float cy = (sigmoidf_(v0.y) * 2.0f - 0.5f + (float)y) * st;
        float tw = sigmoidf_(v0.z) * 2.0f;
        float th = sigmoidf_(v0.w) * 2.0f;
        float w = tw * tw * aw;
        float h = th * th * ah;
        bb.x = cx - w * 0.5f;
        bb.y = cy - h * 0.5f;
        bb.z = cx + w * 0.5f;
        bb.w = cy + h * 0.5f;
        float4 c0 = p[1], c1 = p[2], c2 = p[3], c3 = p[4];
        float vals[15] = { c0.y, c0.z, c0.w,
                           c1.x, c1.y, c1.z, c1.w,
                           c2.x, c2.y, c2.z, c2.w,
                           c3.x, c3.y, c3.z, c3.w };
        float bv = vals[0]; int bi = 0;
        for (int k = 1; k < 15; ++k) if (vals[k] > bv) { bv = vals[k]; bi = k; }
        cls = (float)bi;
    }
    ((float4*)sel_box)[t] = bb;
    sel_cls[t] = cls;
}

// ---------------------------------------------------------------- IoU mask (tiled)
// maskT[img][jt][i] = 64-bit word: bit b set <=> j=jt*64+b > i and IoU > 0.45.
// One wave per 64x64 tile; lane = j. j-boxes in registers, i-boxes via
// wave-uniform LDS broadcast (conflict-free). Row word = __ballot(pred).
// Tiles with jt < it are all-zero (j<i) -> store 0, skip compute.
__global__ __launch_bounds__(256) void k_mask(const float* __restrict__ sel_box,
                                              unsigned long long* __restrict__ maskT) {
    __shared__ float4 boxi[64];
    __shared__ float areai[64];
    int img = blockIdx.x >> 6;
    int rem = blockIdx.x & 63;
    int it = rem >> 2;          // 0..15
    int q  = rem & 3;           // 0..3
    int t = threadIdx.x;
    int wv = t >> 6;            // wave 0..3
    int lane = t & 63;
    const float4* bsrc = (const float4*)sel_box + (long)img * NSEL;
    if (t < 64) {
        float4 b = bsrc[it * 64 + t];
        boxi[t] = b;
        areai[t] = (b.z - b.x) * (b.w - b.y);
    }
    __syncthreads();
    int jt = q * 4 + wv;        // 0..15
    unsigned long long* dst =
        maskT + ((long)img * 16 + jt) * NSEL + it * 64 + lane;
    if (jt < it) { *dst = 0ull; return; }
    float4 bj = bsrc[jt * 64 + lane];
    float aj = (bj.z - bj.x) * (bj.w - bj.y);
    bool diag = (jt == it);
    unsigned long long myword = 0;
    for (int i = 0; i < 64; ++i) {
        float4 bi = boxi[i];
        float ai = areai[i];
        float iw = fminf(bi.z, bj.z) - fmaxf(bi.x, bj.x);
        float ih = fminf(bi.w, bj.w) - fmaxf(bi.y, bj.y);
        iw = fmaxf(iw, 0.0f);
        ih = fmaxf(ih, 0.0f);
        float inter = iw * ih;
        float iou = inter / (ai + aj - inter + 1e-7f);
        bool pred = (iou > IOU_T) && (!diag || lane > i);
        unsigned long long bal = __ballot(pred);
        if (lane == i) myword = bal;
    }
    *dst = myword;
}

// ---------------------------------------------------------------- greedy sweep
// One wave per image. Lanes 0..15 hold the 16 keep words (split lo/hi 32-bit).
// Mask rows register-prefetched (double-buffered, 32 rows/chunk); serialized
// chain is just predicated v_and -> v_readlane -> s_and.
// Transposed layout: lane w reads maskT[img][w][row] = lp[row].
#define SWEEP_CHUNK(kc, CUR, NXT, HALF)                                   \
    {                                                                     \
        if ((kc) + 1 < 32) {                                              \
            _Pragma("unroll")                                             \
            for (int d = 0; d < 32; ++d)                                  \
                NXT[d] = ldv ? lp[((kc) + 1) * 32 + d] : 0ull;            \
        }                                                                 \
        int widx = (kc) >> 1;                                             \
        _Pragma("unroll")                                                 \
        for (int d = 0; d < 32; ++d) {                                    \
            unsigned cur = (unsigned)__builtin_amdgcn_readlane(           \
                (int)(HALF), widx);                                       \
            unsigned long long mm =                                       \
                (cur & (1u << d)) ? CUR[d] : 0ull;                        \
            kwlo &= ~(unsigned)mm;                                        \
            kwhi &= ~(unsigned)(mm >> 32);                                \
        }                                                                 \
    }

__global__ __launch_bounds__(64) void k_sweep(const float* __restrict__ sel_score,
                                              const unsigned long long* __restrict__ maskT,
                                              unsigned long long* __restrict__ keep) {
    int img = blockIdx.x;
    int lane = threadIdx.x;
    const float* sc = sel_score + img * NSEL;
    unsigned long long kw = 0;
    for (int g = 0; g < 16; ++g) {
        unsigned long long bal = __ballot(sc[g * 64 + lane] > CONF_T);
        if (lane == g) kw = bal;
    }
    unsigned kwlo = (unsigned)kw;
    unsigned kwhi = (unsigned)(kw >> 32);
    bool ldv = lane < 16;
    const unsigned long long* lp =
        maskT + (long)img * 16 * NSEL + (long)(ldv ? lane : 0) * NSEL;
    unsigned long long bufA[32], bufB[32];
#pragma unroll
    for (int d = 0; d < 32; ++d) bufA[d] = ldv ? lp[d] : 0ull;
    for (int kc = 0; kc < 32; kc += 2) {
        SWEEP_CHUNK(kc,     bufA, bufB, kwlo);
        SWEEP_CHUNK(kc + 1, bufB, bufA, kwhi);
    }
    if (lane < 16)
        keep[img * 16 + lane] =
            ((unsigned long long)kwhi << 32) | (unsigned long long)kwlo;
}

// ---------------------------------------------------------------- output
__global__ __launch_bounds__(1024) void k_out(const float* __restrict__ sel_score,
                                              const float* __restrict__ sel_box,
                                              const float* __restrict__ sel_cls,
                                              const unsigned long long* __restrict__ keep,
                                              float* __restrict__ out) {
    __shared__ unsigned int wsum[16];
    int img = blockIdx.x, t = threadIdx.x;
    float* o = out + (long)img * NDET * 6;
    for (int e = t; e < NDET * 6; e += 1024) o[e] = 0.0f;
    bool kept = (keep[img * 16 + (t >> 6)] >> (t & 63)) & 1ull;
    unsigned long long bal = __ballot(kept);
    int lane = t & 63, wid = t >> 6;
    int lrank = __popcll(bal & ((1ull << lane) - 1ull));
    if (lane == 0) wsum[wid] = (unsigned)__popcll(bal);
    __syncthreads();
    int off = 0;
    for (int ww = 0; ww < wid; ++ww) off += (int)wsum[ww];
    int rank = off + lrank;
    if (kept && rank < NDET) {
        float4 b = ((const float4*)sel_box)[img * NSEL + t];
        float s = sel_score[img * NSEL + t];
        float c = sel_cls[img * NSEL + t];
        float* row = o + rank * 6;
        row[0] = b.x; row[1] = b.y; row[2] = b.z; row[3] = b.w;
        row[4] = s;   row[5] = c;
    }
}

// ---------------------------------------------------------------- launch
extern "C" void kernel_launch(void* const* d_in, const int* in_sizes, int n_in,
                              void* d_out, int out_size, void* d_ws, size_t ws_size,
                              hipStream_t stream) {
    const float* r0   = (const float*)d_in[0];
    const float* r1   = (const float*)d_in[1];
    const float* r2   = (const float*)d_in[2];
    const float* strd = (const float*)d_in[3];
    const float* ag   = (const float*)d_in[4];

    char* ws = (char*)d_ws;
    size_t off = 0;
    auto alloc = [&](size_t bytes) -> void* {
        void* p = ws + off;
        off += (bytes + 255) & ~(size_t)255;
        return p;
    };
    float* scores              = (float*)alloc((size_t)NB * NPRED * 4);
    unsigned long long* cand   = (unsigned long long*)alloc((size_t)NB * NCAND * 8);
    float* sel_score           = (float*)alloc((size_t)NB * NSEL * 4);
    int* sel_idx               = (int*)alloc((size_t)NB * NSEL * 4);
    float* sel_box             = (float*)alloc((size_t)NB * NSEL * 16);
    float* sel_cls             = (float*)alloc((size_t)NB * NSEL * 4);
    unsigned long long* maskT  = (unsigned long long*)alloc((size_t)NB * 16 * NSEL * 8);
    unsigned long long* keep   = (unsigned long long*)alloc((size_t)NB * 16 * 8);
    float* out = (float*)d_out;

    k_score<<<(NB * NPRED + 255) / 256, 256, 0, stream>>>(r0, r1, r2, scores);
    k_select<<<NB, 1024, 0, stream>>>(scores, cand);
    k_sort<<<NB, 1024, 0, stream>>>(cand, sel_score, sel_idx);
    k_decode<<<(NB * NSEL + 255) / 256, 256, 0, stream>>>(r0, r1, r2, strd, ag,
                                                          sel_score, sel_idx, sel_box, sel_cls);
    k_mask<<<NB * 64, 256, 0, stream>>>(sel_box, maskT);
    k_sweep<<<NB, 64, 0, stream>>>(sel_score, maskT, keep);
    k_out<<<NB, 1024, 0, stream>>>(sel_score, sel_box, sel_cls, keep, out);
}